// Round 4
// baseline (147.232 us; speedup 1.0000x reference)
//
#include <hip/hip_runtime.h>
#include <math.h>

#define BATCH  512
#define NROWS  256
#define NVECS  8
#define VSIZE  128
#define DIM    1024   // NVECS*VSIZE
#define NCOMBO 256

// ---------------------------------------------------------------------------
// R4: hoisted PER-SUB-VECTOR w-norms (R3 fix). Tile = 8b x 8r, 256 threads,
// grid 64x32.
//
// R3 failed because it hoisted the FULL-ROW norm; the reference needs the
// norm of each 128-elem chunk n (the 3-step butterfly in the original code
// was a per-8-lane-group reduce for exactly this reason). R4 hoists the
// 8x8 = 64 inverse sub-norms into iwS[r*8+n], computed once per block by
// the 4 waves (2 W-rows each) with the same koff lane layout as the dot
// phase. The r-loop drops 16 FMA + 1/3 of the butterfly per iteration.
// ---------------------------------------------------------------------------
__global__ __launch_bounds__(256) void fused_kernel(
    const float* __restrict__ q, const float* __restrict__ w,
    float* __restrict__ out) {
  __shared__ __align__(16) float Ws[8 * 1056];   // 33 KB: 8 rows, 8x(128+4)
  __shared__ __align__(16) float Cs[8 * 64];     // 2 KB: [b'][r*8+n]
  __shared__ float iwS[64];                      // [r][n] inverse sub-norms
  const int t    = threadIdx.x;
  const int wv   = t >> 6, lane = t & 63;
  const int bs   = blockIdx.x * 8, rs = blockIdx.y * 8;
  const int n    = lane >> 3, c = lane & 7;
  const int koff = n * VSIZE + c * 16;
  const int b0   = bs + 2 * wv;

  // stage W tile (8 x 1024 floats): consecutive threads -> consecutive 16B
  #pragma unroll
  for (int i = 0; i < 8; ++i) {
    int f = i * 256 + t;        // float4 index 0..2047
    int g = f << 2;             // element index
    int row = g >> 10, e = g & 1023;
    float4 v = *(const float4*)(w + (size_t)(rs + row) * DIM + e);
    *(float4*)(Ws + row * 1056 + (e >> 7) * 132 + (e & 127)) = v;
  }

  // w sub-norms: wave wv handles rows 2wv, 2wv+1; same koff layout as dots.
  // Per row: 16 contiguous floats/lane from global (L2-hot), 16 FMA,
  // 3-step group butterfly -> chunk-n sum in each 8-lane group.
  #pragma unroll
  for (int h = 0; h < 2; ++h) {
    const int row = 2 * wv + h;
    const float* Wr = w + (size_t)(rs + row) * DIM + koff;
    float ss = 0.f;
    #pragma unroll
    for (int jj = 0; jj < 4; ++jj) {
      float4 v = *(const float4*)(Wr + 4 * jj);
      ss = fmaf(v.x, v.x, ss); ss = fmaf(v.y, v.y, ss);
      ss = fmaf(v.z, v.z, ss); ss = fmaf(v.w, v.w, ss);
    }
    #pragma unroll
    for (int m = 1; m <= 4; m <<= 1) ss += __shfl_xor(ss, m, 64);
    if (c == 0) iwS[row * 8 + n] = 1.0f / fmaxf(sqrtf(ss), 1e-8f);
  }

  // Q rows -> registers; inline sub-vector inverse norms via butterfly.
  float4 qa[4], qb[4];
  float qs0 = 0.f, qs1 = 0.f;
  {
    const float* Q0 = q + (size_t)b0 * DIM + koff;
    #pragma unroll
    for (int j = 0; j < 4; ++j) {
      qa[j] = *(const float4*)(Q0 + 4 * j);
      qb[j] = *(const float4*)(Q0 + DIM + 4 * j);
      qs0 = fmaf(qa[j].x, qa[j].x, qs0); qs0 = fmaf(qa[j].y, qa[j].y, qs0);
      qs0 = fmaf(qa[j].z, qa[j].z, qs0); qs0 = fmaf(qa[j].w, qa[j].w, qs0);
      qs1 = fmaf(qb[j].x, qb[j].x, qs1); qs1 = fmaf(qb[j].y, qb[j].y, qs1);
      qs1 = fmaf(qb[j].z, qb[j].z, qs1); qs1 = fmaf(qb[j].w, qb[j].w, qs1);
    }
  }
  #pragma unroll
  for (int m = 1; m <= 4; m <<= 1) {
    qs0 += __shfl_xor(qs0, m, 64);
    qs1 += __shfl_xor(qs1, m, 64);
  }
  const float iq0 = 1.0f / fmaxf(sqrtf(qs0), 1e-8f);
  const float iq1 = 1.0f / fmaxf(sqrtf(qs1), 1e-8f);

  __syncthreads();   // covers Ws staging AND iwS

  // ---- Phase 1: dots -> Cs (LDS) ---------------------------------------
  const float* Wb = Ws + n * 132 + c * 16;
  #pragma unroll 2
  for (int r = 0; r < 8; ++r) {
    const float* Wr = Wb + r * 1056;
    float s0 = 0.f, s1 = 0.f;
    #pragma unroll
    for (int j = 0; j < 4; ++j) {
      float4 w4 = *(const float4*)(Wr + 4 * j);
      s0 = fmaf(qa[j].x, w4.x, s0); s0 = fmaf(qa[j].y, w4.y, s0);
      s0 = fmaf(qa[j].z, w4.z, s0); s0 = fmaf(qa[j].w, w4.w, s0);
      s1 = fmaf(qb[j].x, w4.x, s1); s1 = fmaf(qb[j].y, w4.y, s1);
      s1 = fmaf(qb[j].z, w4.z, s1); s1 = fmaf(qb[j].w, w4.w, s1);
    }
    #pragma unroll
    for (int m = 1; m <= 4; m <<= 1) {
      s0 += __shfl_xor(s0, m, 64);
      s1 += __shfl_xor(s1, m, 64);
    }
    const float iw  = iwS[r * 8 + n];  // per-group broadcast, conflict-free
    const float cs0 = fmaxf(s0 * iq0 * iw, 0.f);
    const float cs1 = fmaxf(s1 * iq1 * iw, 0.f);
    // park wave-uniform results: lane 8n writes cs0, lane 8n+1 writes cs1
    float csv = (c == 0) ? cs0 : cs1;
    if (c < 2) Cs[(2 * wv + c) * 64 + r * 8 + n] = csv;
  }

  // ---- Phase 2: expand + stream stores ---------------------------------
  // No barrier: each wave reads only the Cs rows it wrote itself.
  const bool m2 = lane & 1,  m3 = lane & 2,  m4 = lane & 4;
  const bool m5 = lane & 8,  m6 = lane & 16, m7 = lane & 32;
  float* outL = out + lane * 4;
  #pragma unroll 4
  for (int pi = 0; pi < 16; ++pi) {
    const int p = wv * 16 + pi;           // p>>3 = b' in {2wv,2wv+1}, p&7 = r
    float4 va = *(const float4*)(Cs + p * 8);      // broadcast read: cs[0..3]
    float4 vb = *(const float4*)(Cs + p * 8 + 4);  // broadcast read: cs[4..7]
    float t2 = m2 ? 1.f - va.z : va.z;
    float t3 = m3 ? 1.f - va.w : va.w;
    float t4 = m4 ? 1.f - vb.x : vb.x;
    float t5 = m5 ? 1.f - vb.y : vb.y;
    float t6 = m6 ? 1.f - vb.z : vb.z;
    float t7 = m7 ? 1.f - vb.w : vb.w;
    float base = ((t2 * t3) * (t4 * t5)) * (t6 * t7);
    float c0 = va.x, c1 = va.y;
    float4 o;
    o.x = base * (c0 * c1);
    o.y = base * ((1.f - c0) * c1);
    o.z = base * (c0 * (1.f - c1));
    o.w = base * ((1.f - c0) * (1.f - c1));
    *(float4*)(outL +
        ((size_t)(bs + (p >> 3)) * NROWS + (rs + (p & 7))) * NCOMBO) = o;
  }
}

// ---------------------------------------------------------------------------
extern "C" void kernel_launch(void* const* d_in, const int* in_sizes, int n_in,
                              void* d_out, int out_size, void* d_ws, size_t ws_size,
                              hipStream_t stream) {
  const float* query  = (const float*)d_in[0];   // [512][1024]
  const float* weight = (const float*)d_in[1];   // [256][1024]
  float* out = (float*)d_out;                    // [512][256][256]
  (void)d_ws; (void)ws_size;

  hipLaunchKernelGGL(fused_kernel, dim3(64, 32), dim3(256), 0, stream,
                     query, weight, out);
}